// Round 18
// baseline (145.135 us; speedup 1.0000x reference)
//
#include <hip/hip_runtime.h>
#include <hip/hip_bf16.h>
#include <cstdint>
#include <cstddef>

typedef __bf16 bf16_t;
typedef __attribute__((ext_vector_type(8))) __bf16 bf16x8;
typedef __attribute__((ext_vector_type(4))) float f32x4;
typedef __attribute__((ext_vector_type(16))) float f32x16;
typedef __attribute__((ext_vector_type(4))) unsigned int u32x4;

#define ATT_EPS 1e-4f

__device__ __forceinline__ f32x4 mfma_bf16(bf16x8 a, bf16x8 b, f32x4 c) {
  return __builtin_amdgcn_mfma_f32_16x16x32_bf16(a, b, c, 0, 0, 0);
}
__device__ __forceinline__ f32x16 mfma32(bf16x8 a, bf16x8 b, f32x16 c) {
  return __builtin_amdgcn_mfma_f32_32x32x16_bf16(a, b, c, 0, 0, 0);
}
__device__ __forceinline__ unsigned cvtpk_bf16(float lo, float hi) {
  unsigned r;
  asm("v_cvt_pk_bf16_f32 %0, %1, %2" : "=v"(r) : "v"(lo), "v"(hi));
  return r;
}

#define GLDS16(g, l)                                                          \
  __builtin_amdgcn_global_load_lds(                                           \
      (const __attribute__((address_space(1))) void*)(g),                     \
      (__attribute__((address_space(3))) void*)(l), 16, 0, 0)

// raw barrier + counted waits (gemm1 only; NOT __syncthreads: that drains vmcnt)
#define BARRAW() asm volatile("s_barrier" ::: "memory")
#define WAITVN(n) asm volatile("s_waitcnt vmcnt(" #n ")" ::: "memory")

// ------------- prep: W transposes + X f32->bf16 convert, one launch
__global__ __launch_bounds__(256) void prep_kernel(
    const float* __restrict__ Wi, bf16_t* __restrict__ WiT,
    const float* __restrict__ Wo, bf16_t* __restrict__ WoT,
    const float* __restrict__ X, bf16_t* __restrict__ Xb) {
  __shared__ float T[64][65];
  if (blockIdx.y >= 20) {
    int i = ((blockIdx.y - 20) * 64 + blockIdx.x) * 256 + threadIdx.x;
    const f32x4* src = (const f32x4*)X + (size_t)i * 4;
    f32x4 a = src[0], b = src[1], c = src[2], d = src[3];
    bf16x8 o0, o1;
    o0[0] = (__bf16)a[0]; o0[1] = (__bf16)a[1]; o0[2] = (__bf16)a[2]; o0[3] = (__bf16)a[3];
    o0[4] = (__bf16)b[0]; o0[5] = (__bf16)b[1]; o0[6] = (__bf16)b[2]; o0[7] = (__bf16)b[3];
    o1[0] = (__bf16)c[0]; o1[1] = (__bf16)c[1]; o1[2] = (__bf16)c[2]; o1[3] = (__bf16)c[3];
    o1[4] = (__bf16)d[0]; o1[5] = (__bf16)d[1]; o1[6] = (__bf16)d[2]; o1[7] = (__bf16)d[3];
    ((bf16x8*)Xb)[(size_t)i * 2] = o0;
    ((bf16x8*)Xb)[(size_t)i * 2 + 1] = o1;
    return;
  }
  int tx = threadIdx.x & 63, ty = threadIdx.x >> 6;
  const float* W;
  bf16_t* Wt;
  int c0, r0, R, C;
  if (blockIdx.y < 16) {
    W = Wi; Wt = WiT; R = 1024; C = 4096;
    c0 = blockIdx.x * 64; r0 = blockIdx.y * 64;
  } else {
    int idx = (blockIdx.y - 16) * 64 + blockIdx.x;
    if (idx >= 256) return;
    W = Wo; Wt = WoT; R = 1024; C = 1024;
    c0 = (idx & 15) * 64; r0 = (idx >> 4) * 64;
  }
#pragma unroll
  for (int i = 0; i < 16; ++i) {
    int rr = ty * 16 + i;
    T[rr][tx] = W[(size_t)(r0 + rr) * C + c0 + tx];
  }
  __syncthreads();
#pragma unroll
  for (int i = 0; i < 16; ++i) {
    int cc = ty * 16 + i;
    Wt[(size_t)(c0 + cc) * R + r0 + tx] = (bf16_t)T[tx][cc];
  }
}

// --------------------------------------------- gemm1: 256x256 tile, BK=32,
// 4-buffer / 3-deep prefetch, counted vmcnt + raw s_barrier. Fused epilogue.
__global__ __launch_bounds__(512, 2) void gemm1_kernel(
    const bf16_t* __restrict__ A, const bf16_t* __restrict__ Bt,
    const float* __restrict__ bias, bf16_t* __restrict__ P,
    float* __restrict__ Q2, bf16_t* __restrict__ K2E, bf16_t* __restrict__ VtG) {
  __shared__ bf16_t As[4][2][128 * 32];  // 64KB
  __shared__ bf16_t Bs[4][2][128 * 32];  // 64KB

  const int K = 1024, N = 4096;
  int tid = threadIdx.x, lane = tid & 63, wv = tid >> 6;
  int l15 = lane & 15, lhi = lane >> 4;
  int wm = wv >> 2, wn = wv & 3;
  int swz = (blockIdx.x & 7) * 32 + (blockIdx.x >> 3);  // 256 blocks
  int tm = swz >> 4, tn = swz & 15;
  int m0 = tm << 8, n0 = tn << 8;
  int h = tn;

  int srow = tid >> 2, su = tid & 3;
  int scc = (su ^ ((srow >> 1) & 3)) << 3;  // source col swizzle (2-way max)
  auto stage2 = [&](int t, int pq) {
    int k0 = t * 32 + scc;
    if (pq == 0) {
      GLDS16(A + (size_t)(m0 + srow) * K + k0, &As[t & 3][0][tid * 8]);
      GLDS16(A + (size_t)(m0 + 128 + srow) * K + k0, &As[t & 3][1][tid * 8]);
    } else {
      GLDS16(Bt + (size_t)(n0 + srow) * K + k0, &Bs[t & 3][0][tid * 8]);
      GLDS16(Bt + (size_t)(n0 + 128 + srow) * K + k0, &Bs[t & 3][1][tid * 8]);
    }
  };

  f32x4 zero = {0.f, 0.f, 0.f, 0.f};
  f32x4 acc[8][4];
#pragma unroll
  for (int mf = 0; mf < 8; ++mf)
#pragma unroll
    for (int nf = 0; nf < 4; ++nf) acc[mf][nf] = zero;

  int bh = wn >> 1;
  int cidb = (wn & 1) * 64 + l15;

  stage2(0, 0); stage2(0, 1);
  stage2(1, 0); stage2(1, 1);
  stage2(2, 0); stage2(2, 1);
  WAITVN(8);
  BARRAW();

  for (int t = 0; t < 32; ++t) {
    int buf = t & 3;
    bf16x8 af0[4], bfr[4];
#pragma unroll
    for (int i = 0; i < 4; ++i) {
      int mfr = i * 16 + l15;
      af0[i] = *(const bf16x8*)&As[buf][wm][mfr * 32 + ((lhi ^ ((mfr >> 1) & 3)) << 3)];
    }
#pragma unroll
    for (int nf = 0; nf < 4; ++nf) {
      int cid = cidb + nf * 16;
      bfr[nf] = *(const bf16x8*)&Bs[buf][bh][cid * 32 + ((lhi ^ ((cid >> 1) & 3)) << 3)];
    }
    if (t + 3 < 32) stage2(t + 3, 0);
#pragma unroll
    for (int i = 0; i < 4; ++i)
#pragma unroll
      for (int nf = 0; nf < 4; ++nf)
        acc[i][nf] = mfma_bf16(af0[i], bfr[nf], acc[i][nf]);
    bf16x8 af1[4];
#pragma unroll
    for (int i = 0; i < 4; ++i) {
      int mfr = (4 + i) * 16 + l15;
      af1[i] = *(const bf16x8*)&As[buf][wm][mfr * 32 + ((lhi ^ ((mfr >> 1) & 3)) << 3)];
    }
    if (t + 3 < 32) stage2(t + 3, 1);
#pragma unroll
    for (int i = 0; i < 4; ++i)
#pragma unroll
      for (int nf = 0; nf < 4; ++nf)
        acc[4 + i][nf] = mfma_bf16(af1[i], bfr[nf], acc[4 + i][nf]);
    if (t <= 28) WAITVN(8);
    else if (t == 29) WAITVN(4);
    else if (t == 30) WAITVN(0);
    BARRAW();
  }

#pragma unroll
  for (int nf = 0; nf < 4; ++nf) {
    float bv = bias[n0 + wn * 64 + nf * 16 + l15];
#pragma unroll
    for (int mf = 0; mf < 8; ++mf)
#pragma unroll
      for (int r = 0; r < 4; ++r) acc[mf][nf][r] += bv;
  }

  if (wn != 2) {
#pragma unroll
    for (int nf = 0; nf < 4; ++nf) {
      int col = n0 + wn * 64 + nf * 16 + l15;
#pragma unroll
      for (int mf = 0; mf < 8; ++mf) {
        int rowb = m0 + wm * 128 + mf * 16 + lhi * 4;
#pragma unroll
        for (int r = 0; r < 4; ++r)
          P[(size_t)(rowb + r) * N + col] = (bf16_t)acc[mf][nf][r];
      }
    }
  }

  if (wn < 2) {
#pragma unroll
    for (int mf = 0; mf < 8; ++mf)
#pragma unroll
      for (int r = 0; r < 4; ++r) {
        float s = 0.f;
#pragma unroll
        for (int nf = 0; nf < 4; ++nf) s += acc[mf][nf][r] * acc[mf][nf][r];
        s += __shfl_xor(s, 1);
        s += __shfl_xor(s, 2);
        s += __shfl_xor(s, 4);
        s += __shfl_xor(s, 8);
        if (l15 == 0) {
          int row = m0 + wm * 128 + mf * 16 + lhi * 4 + r;
          if (wn == 0) {
            Q2[h * 4096 + row] = s;
          } else {
            __bf16 kh = (__bf16)s;
            __bf16 kl = (__bf16)(s - (float)kh);
            bf16x8 rw;
            rw[0] = kh; rw[1] = kl;
            rw[2] = (__bf16)1.f; rw[3] = (__bf16)1.f;
            rw[4] = (__bf16)0.f; rw[5] = (__bf16)0.f;
            rw[6] = (__bf16)0.f; rw[7] = (__bf16)0.f;
            *(bf16x8*)&K2E[((size_t)h * 4096 + row) * 8] = rw;
          }
        }
      }
  }

  bf16_t* T = &As[0][0][0];  // [64][264] = 33.8KB
  if (wn == 2) {
#pragma unroll
    for (int mf = 0; mf < 8; ++mf)
#pragma unroll
      for (int nf = 0; nf < 4; ++nf)
#pragma unroll
        for (int r = 0; r < 4; ++r) {
          int row = wm * 128 + mf * 16 + lhi * 4 + r;
          int e = nf * 16 + l15;
          int prow = (row & ~15) | ((row & 3) | ((row & 4) << 1) | ((row & 8) >> 1));
          T[e * 264 + prow] = (bf16_t)acc[mf][nf][r];
        }
  }
  __syncthreads();
  {
    int e = tid >> 3, c0 = (tid & 7) * 32;
    bf16_t* dst = VtG + (size_t)(h * 64 + e) * 4096 + m0 + c0;
#pragma unroll
    for (int j = 0; j < 4; ++j)
      *(bf16x8*)&dst[j * 8] = *(bf16x8*)&T[e * 264 + c0 + j * 8];
  }
}

// ------------------------------------------------------------------- gemm2
template <int OUTF32>
__global__ __launch_bounds__(256, 2) void gemm_kernel(
    const bf16_t* __restrict__ A, const bf16_t* __restrict__ Bt,
    const float* __restrict__ bias, void* __restrict__ Cout,
    int M, int N, int K) {
  __shared__ bf16_t As[2][128 * 64];
  __shared__ bf16_t Bs[2][128 * 64];
  int tid = threadIdx.x, lane = tid & 63, wv = tid >> 6;
  int l15 = lane & 15, lhi = lane >> 4;
  int NT = N >> 7;
  int nwg = gridDim.x;
  int qq = nwg >> 3;
  int swz = (blockIdx.x & 7) * qq + (blockIdx.x >> 3);
  int tm = swz / NT, tn = swz % NT;
  int m0 = tm << 7, n0 = tn << 7;
  int wm = (wv >> 1) << 6, wn = (wv & 1) << 6;
  int KT = K >> 6;

  auto stage = [&](int buf, int kt) {
    int k0 = kt << 6;
#pragma unroll
    for (int s = 0; s < 4; ++s) {
      int t = s * 256 + tid;
      int row = t >> 3, u = t & 7;
      int cc = (u ^ (row & 7)) << 3;
      GLDS16(A + (size_t)(m0 + row) * K + k0 + cc, &As[buf][t * 8]);
    }
#pragma unroll
    for (int s = 0; s < 4; ++s) {
      int t = s * 256 + tid;
      int row = t >> 3, u = t & 7;
      int cc = (u ^ (row & 7)) << 3;
      GLDS16(Bt + (size_t)(n0 + row) * K + k0 + cc, &Bs[buf][t * 8]);
    }
  };

  f32x4 zero = {0.f, 0.f, 0.f, 0.f};
  f32x4 acc[4][4];
#pragma unroll
  for (int ms = 0; ms < 4; ++ms)
#pragma unroll
    for (int ns = 0; ns < 4; ++ns) acc[ms][ns] = zero;

  stage(0, 0);
  __syncthreads();
  int cur = 0;
  for (int kt = 0; kt < KT; ++kt) {
    if (kt + 1 < KT) stage(cur ^ 1, kt + 1);
#pragma unroll
    for (int ks = 0; ks < 2; ++ks) {
      bf16x8 af[4], bfr[4];
#pragma unroll
      for (int ms = 0; ms < 4; ++ms) {
        int row = wm + ms * 16 + l15;
        af[ms] = *(const bf16x8*)&As[cur][row * 64 + (((ks * 4 + lhi) ^ (row & 7)) << 3)];
      }
#pragma unroll
      for (int ns = 0; ns < 4; ++ns) {
        int col = wn + ns * 16 + l15;
        bfr[ns] = *(const bf16x8*)&Bs[cur][col * 64 + (((ks * 4 + lhi) ^ (col & 7)) << 3)];
      }
#pragma unroll
      for (int ms = 0; ms < 4; ++ms)
#pragma unroll
        for (int ns = 0; ns < 4; ++ns)
          acc[ms][ns] = mfma_bf16(af[ms], bfr[ns], acc[ms][ns]);
    }
    __syncthreads();
    cur ^= 1;
  }

#pragma unroll
  for (int ns = 0; ns < 4; ++ns) {
    int col = n0 + wn + ns * 16 + l15;
    float bv = bias[col];
#pragma unroll
    for (int ms = 0; ms < 4; ++ms) {
      int rowb = m0 + wm + ms * 16 + lhi * 4;
#pragma unroll
      for (int r = 0; r < 4; ++r) {
        float v = acc[ms][ns][r] + bv;
        if (OUTF32)
          ((float*)Cout)[(size_t)(rowb + r) * N + col] = v;
        else
          ((bf16_t*)Cout)[(size_t)(rowb + r) * N + col] = (bf16_t)v;
      }
    }
  }
}

// ------------------------------------------------------- fused Shepard attention
// R18: 2 tiles per iteration, 4-buffer ring, manual 2x unroll (compile-time buf
// indices). The two QK D-chains are independent -> intra-wave ILP x2 on the
// serial section; barriers halve; and the plain __syncthreads vmcnt drain is
// now covered by a full 2-tile compute phase (~1000cyc >= HBM latency).
__global__ __launch_bounds__(512, 4) void attn_kernel(
    const bf16_t* __restrict__ P, const bf16_t* __restrict__ VtG,
    const float* __restrict__ Q2, const bf16_t* __restrict__ K2E,
    bf16_t* __restrict__ H) {
  __shared__ union Smem {
    struct {
      bf16_t Ks[4][64 * 64];   // 32KB
      bf16_t Vts[4][64 * 64];  // 32KB
      bf16_t K2e[4][64 * 8];   // 4KB
    } l;
    float Comb[4][64][33];     // 33.8KB
  } sm;
  __shared__ float invLds[4][32];

  int tid = threadIdx.x, lane = tid & 63, wv = tid >> 6;
  int l31 = lane & 31, hi = lane >> 5, hi4 = hi * 4;
  int qw = wv & 3, sw = wv >> 2;
  int sOff = sw * 32;
  int swz = (blockIdx.x & 7) * 64 + (blockIdx.x >> 3);  // 512 blocks
  int hb = swz >> 4, qt = swz & 15;
  int h = hb >> 1, b = hb & 1;
  int rowbase = b * 2048;
  const bf16_t* Pq = P + (size_t)rowbase * 4096 + h * 256;
  const bf16_t* Pk = Pq + 64;
  const bf16_t* Pg = Pq + 192;
  const bf16_t* Vg = VtG + (size_t)h * 64 * 4096 + rowbase;
  const float* Q2g = Q2 + h * 4096 + rowbase;
  const bf16_t* K2Eg = K2E + ((size_t)h * 4096 + rowbase) * 8;
  int q0 = qt * 128 + qw * 32;

  auto stageKV = [&](int buf, int s0) {
    {
      int row = tid >> 3, u = tid & 7;
      int cc = (u ^ (row & 7)) << 3;
      GLDS16(Pk + (size_t)(s0 + row) * 4096 + cc, &sm.l.Ks[buf][tid * 8]);
    }
    {
      int row = tid >> 3, u = tid & 7;
      int cc = (u ^ (row & 7)) << 3;
      GLDS16(Vg + (size_t)row * 4096 + s0 + cc, &sm.l.Vts[buf][tid * 8]);
    }
    if (tid < 64)
      GLDS16(K2Eg + (size_t)(s0 + tid) * 8, &sm.l.K2e[buf][tid * 8]);
  };

  bf16x8 qm[4];
#pragma unroll
  for (int db = 0; db < 4; ++db) {
    bf16x8 q = *(const bf16x8*)(Pq + (size_t)(q0 + l31) * 4096 + db * 16 + hi * 8);
    u32x4 u = *(u32x4*)&q;
    u = (u ^ 0x80008000u) + 0x00800080u;
    qm[db] = *(bf16x8*)&u;
  }
  float q2s = Q2g[q0 + l31];
  __bf16 q2h = (__bf16)q2s;
  __bf16 q2l = (__bf16)(q2s - (float)q2h);
  bf16x8 qmE;
  qmE[0] = hi ? (__bf16)0.f : (__bf16)1.f;
  qmE[1] = qmE[0];
  qmE[2] = hi ? (__bf16)0.f : q2h;
  qmE[3] = hi ? (__bf16)0.f : q2l;
  qmE[4] = (__bf16)0.f; qmE[5] = (__bf16)0.f;
  qmE[6] = (__bf16)0.f; qmE[7] = (__bf16)0.f;

  f32x16 zero16;
#pragma unroll
  for (int r = 0; r < 16; ++r) zero16[r] = 0.f;

  f32x16 nacc0 = zero16, nacc1 = zero16;
  float dacc0 = 0.f, dacc1 = 0.f;

  // seed MFMA + QK^T chain for one tile (pure function of buffer)
  auto qkD = [&](const bf16_t* KsC, const bf16_t* K2eC) -> f32x16 {
    int srow = sOff + l31;
    bf16x8 ke = *(const bf16x8*)&K2eC[srow * 8];
    u32x4 keu = *(u32x4*)&ke;
    u32x4 kz;
    kz[0] = hi ? 0u : keu[0];
    kz[1] = hi ? 0u : keu[1];
    kz[2] = 0u; kz[3] = 0u;
    bf16x8 kfE = *(bf16x8*)&kz;
    f32x16 D = mfma32(kfE, qmE, zero16);
#pragma unroll
    for (int db = 0; db < 4; ++db) {
      bf16x8 kf = *(const bf16x8*)&KsC[srow * 64 + (((db * 2 + hi) ^ (srow & 7)) << 3)];
      D = mfma32(kf, qm[db], D);
    }
    return D;
  };
  // w = 1/d2, denom accumulate, pack, PV
  auto pv = [&](f32x16 D, const bf16_t* VtC) {
    float p[16];
#pragma unroll
    for (int r = 0; r < 16; ++r) {
      float w = __builtin_amdgcn_rcpf(fmaxf(D[r], 1e-12f));
      if (r & 1) dacc1 += w; else dacc0 += w;
      p[r] = w;
    }
    u32x4 w0v = {cvtpk_bf16(p[0], p[1]), cvtpk_bf16(p[2], p[3]),
                 cvtpk_bf16(p[4], p[5]), cvtpk_bf16(p[6], p[7])};
    u32x4 w1v = {cvtpk_bf16(p[8], p[9]), cvtpk_bf16(p[10], p[11]),
                 cvtpk_bf16(p[12], p[13]), cvtpk_bf16(p[14], p[15])};
    bf16x8 pa0 = *(bf16x8*)&w0v;
    bf16x8 pa1 = *(bf16x8*)&w1v;
    int e = l31;
    int ciB = sw * 4;
    bf16x8 vb00 = *(const bf16x8*)&VtC[e * 64 + (((ciB + 0 + hi) ^ (e & 7)) << 3)];
    bf16x8 vb01 = *(const bf16x8*)&VtC[(e + 32) * 64 + (((ciB + 0 + hi) ^ ((e + 32) & 7)) << 3)];
    bf16x8 vb10 = *(const bf16x8*)&VtC[e * 64 + (((ciB + 2 + hi) ^ (e & 7)) << 3)];
    bf16x8 vb11 = *(const bf16x8*)&VtC[(e + 32) * 64 + (((ciB + 2 + hi) ^ ((e + 32) & 7)) << 3)];
    nacc0 = mfma32(pa0, vb00, nacc0);
    nacc1 = mfma32(pa0, vb01, nacc1);
    nacc0 = mfma32(pa1, vb10, nacc0);
    nacc1 = mfma32(pa1, vb11, nacc1);
  };

  // prologue: fill all 4 buffers (tiles 0..3)
  stageKV(0, 0);
  stageKV(1, 64);
  stageKV(2, 128);
  stageKV(3, 192);
  __syncthreads();

  for (int m = 0; m < 8; ++m) {
    int s0 = m * 256;
    // half A: tiles 4m (buf0), 4m+1 (buf1); stage tiles 4m+2,4m+3 (bufs 2,3)
    {
      if (m > 0) { stageKV(2, s0 + 128); stageKV(3, s0 + 192); }
      f32x16 Da = qkD(sm.l.Ks[0], sm.l.K2e[0]);
      f32x16 Db = qkD(sm.l.Ks[1], sm.l.K2e[1]);
      pv(Da, sm.l.Vts[0]);
      pv(Db, sm.l.Vts[1]);
      __syncthreads();
    }
    // half B: tiles 4m+2 (buf2), 4m+3 (buf3); stage tiles 4m+4,4m+5 (bufs 0,1)
    {
      if (m < 7) { stageKV(0, s0 + 256); stageKV(1, s0 + 320); }
      f32x16 Da = qkD(sm.l.Ks[2], sm.l.K2e[2]);
      f32x16 Db = qkD(sm.l.Ks[3], sm.l.K2e[3]);
      pv(Da, sm.l.Vts[2]);
      pv(Db, sm.l.Vts[3]);
      __syncthreads();
    }
  }

  // combine s-halves via Comb (overlays loop buffers; loop's final barrier done)
  if (sw == 1) {
#pragma unroll
    for (int r = 0; r < 16; ++r) {
      sm.Comb[qw][lane][r] = nacc0[r];
      sm.Comb[qw][lane][16 + r] = nacc1[r];
    }
    sm.Comb[qw][lane][32] = dacc0 + dacc1;
  }
  __syncthreads();
  if (sw == 0) {
    float dacc = dacc0 + dacc1 + sm.Comb[qw][lane][32];
#pragma unroll
    for (int r = 0; r < 16; ++r) {
      nacc0[r] += sm.Comb[qw][lane][r];
      nacc1[r] += sm.Comb[qw][lane][16 + r];
    }
    dacc += __shfl_xor(dacc, 32);
    float inv = __builtin_amdgcn_rcpf(ATT_EPS + dacc);
    if (lane < 32) invLds[qw][l31] = inv;
    __builtin_amdgcn_s_waitcnt(0);
#pragma unroll
    for (int r = 0; r < 16; ++r) {
      int q = (r & 3) + 8 * (r >> 2) + hi4;
      int tq = q0 + q;
      float iv = invLds[qw][q];
      float g0 = (float)Pg[(size_t)tq * 4096 + l31];
      float g1 = (float)Pg[(size_t)tq * 4096 + 32 + l31];
      H[(size_t)(rowbase + tq) * 1024 + h * 64 + l31] = (bf16_t)(g0 * nacc0[r] * iv);
      H[(size_t)(rowbase + tq) * 1024 + h * 64 + 32 + l31] = (bf16_t)(g1 * nacc1[r] * iv);
    }
  }
}

// ------------------------------------------------------------------ launcher
extern "C" void kernel_launch(void* const* d_in, const int* in_sizes, int n_in,
                              void* d_out, int out_size, void* d_ws, size_t ws_size,
                              hipStream_t stream) {
  const float* X     = (const float*)d_in[0];
  const float* W_in  = (const float*)d_in[1];
  const float* b_in  = (const float*)d_in[2];
  const float* W_out = (const float*)d_in[3];
  const float* b_out = (const float*)d_in[4];

  char* ws = (char*)d_ws;
  bf16_t* Xb  = (bf16_t*)(ws);                        // 8 MB
  bf16_t* WbT = (bf16_t*)(ws + ((size_t)8  << 20));   // 8 MB
  bf16_t* WoT = (bf16_t*)(ws + ((size_t)16 << 20));   // 2 MB
  bf16_t* Pb  = (bf16_t*)(ws + ((size_t)18 << 20));   // 32 MB
  bf16_t* Hb  = (bf16_t*)(ws + ((size_t)50 << 20));   // 8 MB
  float*  Q2  = (float*) (ws + ((size_t)58 << 20));   // 256 KB
  // VtG/K2E live in d_out (16 MB, dead until gemm2 overwrites it)
  bf16_t* VtG = (bf16_t*)d_out;                       // 8 MB
  bf16_t* K2E = (bf16_t*)((char*)d_out + ((size_t)8 << 20));  // 1 MB

  prep_kernel<<<dim3(64, 36), 256, 0, stream>>>(W_in, WbT, W_out, WoT, X, Xb);
  gemm1_kernel<<<256, 512, 0, stream>>>(Xb, WbT, b_in, Pb, Q2, K2E, VtG);
  attn_kernel<<<512, 512, 0, stream>>>(Pb, VtG, Q2, K2E, Hb);
  gemm_kernel<1><<<256, 256, 0, stream>>>(Hb, WoT, b_out, d_out, 4096, 1024, 1024);
}

// Round 19
// 127.256 us; speedup vs baseline: 1.1405x; 1.1405x over previous
//
#include <hip/hip_runtime.h>
#include <hip/hip_bf16.h>
#include <cstdint>
#include <cstddef>

typedef __bf16 bf16_t;
typedef __attribute__((ext_vector_type(8))) __bf16 bf16x8;
typedef __attribute__((ext_vector_type(4))) float f32x4;
typedef __attribute__((ext_vector_type(16))) float f32x16;
typedef __attribute__((ext_vector_type(4))) unsigned int u32x4;

#define ATT_EPS 1e-4f

__device__ __forceinline__ f32x4 mfma_bf16(bf16x8 a, bf16x8 b, f32x4 c) {
  return __builtin_amdgcn_mfma_f32_16x16x32_bf16(a, b, c, 0, 0, 0);
}
__device__ __forceinline__ f32x16 mfma32(bf16x8 a, bf16x8 b, f32x16 c) {
  return __builtin_amdgcn_mfma_f32_32x32x16_bf16(a, b, c, 0, 0, 0);
}
__device__ __forceinline__ unsigned cvtpk_bf16(float lo, float hi) {
  unsigned r;
  asm("v_cvt_pk_bf16_f32 %0, %1, %2" : "=v"(r) : "v"(lo), "v"(hi));
  return r;
}

#define GLDS16(g, l)                                                          \
  __builtin_amdgcn_global_load_lds(                                           \
      (const __attribute__((address_space(1))) void*)(g),                     \
      (__attribute__((address_space(3))) void*)(l), 16, 0, 0)

// raw barrier + counted waits (NOT __syncthreads: that drains vmcnt to 0)
#define BARRAW() asm volatile("s_barrier" ::: "memory")
#define WAITVN(n) asm volatile("s_waitcnt vmcnt(" #n ")" ::: "memory")

// ------------- prep: W transposes + X f32->bf16 convert, one launch
__global__ __launch_bounds__(256) void prep_kernel(
    const float* __restrict__ Wi, bf16_t* __restrict__ WiT,
    const float* __restrict__ Wo, bf16_t* __restrict__ WoT,
    const float* __restrict__ X, bf16_t* __restrict__ Xb) {
  __shared__ float T[64][65];
  if (blockIdx.y >= 20) {
    int i = ((blockIdx.y - 20) * 64 + blockIdx.x) * 256 + threadIdx.x;
    const f32x4* src = (const f32x4*)X + (size_t)i * 4;
    f32x4 a = src[0], b = src[1], c = src[2], d = src[3];
    bf16x8 o0, o1;
    o0[0] = (__bf16)a[0]; o0[1] = (__bf16)a[1]; o0[2] = (__bf16)a[2]; o0[3] = (__bf16)a[3];
    o0[4] = (__bf16)b[0]; o0[5] = (__bf16)b[1]; o0[6] = (__bf16)b[2]; o0[7] = (__bf16)b[3];
    o1[0] = (__bf16)c[0]; o1[1] = (__bf16)c[1]; o1[2] = (__bf16)c[2]; o1[3] = (__bf16)c[3];
    o1[4] = (__bf16)d[0]; o1[5] = (__bf16)d[1]; o1[6] = (__bf16)d[2]; o1[7] = (__bf16)d[3];
    ((bf16x8*)Xb)[(size_t)i * 2] = o0;
    ((bf16x8*)Xb)[(size_t)i * 2 + 1] = o1;
    return;
  }
  int tx = threadIdx.x & 63, ty = threadIdx.x >> 6;
  const float* W;
  bf16_t* Wt;
  int c0, r0, R, C;
  if (blockIdx.y < 16) {
    W = Wi; Wt = WiT; R = 1024; C = 4096;
    c0 = blockIdx.x * 64; r0 = blockIdx.y * 64;
  } else {
    int idx = (blockIdx.y - 16) * 64 + blockIdx.x;
    if (idx >= 256) return;
    W = Wo; Wt = WoT; R = 1024; C = 1024;
    c0 = (idx & 15) * 64; r0 = (idx >> 4) * 64;
  }
#pragma unroll
  for (int i = 0; i < 16; ++i) {
    int rr = ty * 16 + i;
    T[rr][tx] = W[(size_t)(r0 + rr) * C + c0 + tx];
  }
  __syncthreads();
#pragma unroll
  for (int i = 0; i < 16; ++i) {
    int cc = ty * 16 + i;
    Wt[(size_t)(c0 + cc) * R + r0 + tx] = (bf16_t)T[tx][cc];
  }
}

// --------------------------------------------- gemm1: 256x256 tile, BK=32,
// 4-buffer / 3-deep prefetch, counted vmcnt + raw s_barrier. Fused epilogue.
__global__ __launch_bounds__(512, 2) void gemm1_kernel(
    const bf16_t* __restrict__ A, const bf16_t* __restrict__ Bt,
    const float* __restrict__ bias, bf16_t* __restrict__ P,
    float* __restrict__ Q2, bf16_t* __restrict__ K2E, bf16_t* __restrict__ VtG) {
  __shared__ bf16_t As[4][2][128 * 32];  // 64KB
  __shared__ bf16_t Bs[4][2][128 * 32];  // 64KB

  const int K = 1024, N = 4096;
  int tid = threadIdx.x, lane = tid & 63, wv = tid >> 6;
  int l15 = lane & 15, lhi = lane >> 4;
  int wm = wv >> 2, wn = wv & 3;
  int swz = (blockIdx.x & 7) * 32 + (blockIdx.x >> 3);  // 256 blocks
  int tm = swz >> 4, tn = swz & 15;
  int m0 = tm << 8, n0 = tn << 8;
  int h = tn;

  int srow = tid >> 2, su = tid & 3;
  int scc = (su ^ ((srow >> 1) & 3)) << 3;  // source col swizzle (2-way max)
  auto stage2 = [&](int t, int pq) {
    int k0 = t * 32 + scc;
    if (pq == 0) {
      GLDS16(A + (size_t)(m0 + srow) * K + k0, &As[t & 3][0][tid * 8]);
      GLDS16(A + (size_t)(m0 + 128 + srow) * K + k0, &As[t & 3][1][tid * 8]);
    } else {
      GLDS16(Bt + (size_t)(n0 + srow) * K + k0, &Bs[t & 3][0][tid * 8]);
      GLDS16(Bt + (size_t)(n0 + 128 + srow) * K + k0, &Bs[t & 3][1][tid * 8]);
    }
  };

  f32x4 zero = {0.f, 0.f, 0.f, 0.f};
  f32x4 acc[8][4];
#pragma unroll
  for (int mf = 0; mf < 8; ++mf)
#pragma unroll
    for (int nf = 0; nf < 4; ++nf) acc[mf][nf] = zero;

  int bh = wn >> 1;
  int cidb = (wn & 1) * 64 + l15;

  stage2(0, 0); stage2(0, 1);
  stage2(1, 0); stage2(1, 1);
  stage2(2, 0); stage2(2, 1);
  WAITVN(8);
  BARRAW();

  for (int t = 0; t < 32; ++t) {
    int buf = t & 3;
    bf16x8 af0[4], bfr[4];
#pragma unroll
    for (int i = 0; i < 4; ++i) {
      int mfr = i * 16 + l15;
      af0[i] = *(const bf16x8*)&As[buf][wm][mfr * 32 + ((lhi ^ ((mfr >> 1) & 3)) << 3)];
    }
#pragma unroll
    for (int nf = 0; nf < 4; ++nf) {
      int cid = cidb + nf * 16;
      bfr[nf] = *(const bf16x8*)&Bs[buf][bh][cid * 32 + ((lhi ^ ((cid >> 1) & 3)) << 3)];
    }
    if (t + 3 < 32) stage2(t + 3, 0);
#pragma unroll
    for (int i = 0; i < 4; ++i)
#pragma unroll
      for (int nf = 0; nf < 4; ++nf)
        acc[i][nf] = mfma_bf16(af0[i], bfr[nf], acc[i][nf]);
    bf16x8 af1[4];
#pragma unroll
    for (int i = 0; i < 4; ++i) {
      int mfr = (4 + i) * 16 + l15;
      af1[i] = *(const bf16x8*)&As[buf][wm][mfr * 32 + ((lhi ^ ((mfr >> 1) & 3)) << 3)];
    }
    if (t + 3 < 32) stage2(t + 3, 1);
#pragma unroll
    for (int i = 0; i < 4; ++i)
#pragma unroll
      for (int nf = 0; nf < 4; ++nf)
        acc[4 + i][nf] = mfma_bf16(af1[i], bfr[nf], acc[4 + i][nf]);
    if (t <= 28) WAITVN(8);
    else if (t == 29) WAITVN(4);
    else if (t == 30) WAITVN(0);
    BARRAW();
  }

#pragma unroll
  for (int nf = 0; nf < 4; ++nf) {
    float bv = bias[n0 + wn * 64 + nf * 16 + l15];
#pragma unroll
    for (int mf = 0; mf < 8; ++mf)
#pragma unroll
      for (int r = 0; r < 4; ++r) acc[mf][nf][r] += bv;
  }

  if (wn != 2) {
#pragma unroll
    for (int nf = 0; nf < 4; ++nf) {
      int col = n0 + wn * 64 + nf * 16 + l15;
#pragma unroll
      for (int mf = 0; mf < 8; ++mf) {
        int rowb = m0 + wm * 128 + mf * 16 + lhi * 4;
#pragma unroll
        for (int r = 0; r < 4; ++r)
          P[(size_t)(rowb + r) * N + col] = (bf16_t)acc[mf][nf][r];
      }
    }
  }

  if (wn < 2) {
#pragma unroll
    for (int mf = 0; mf < 8; ++mf)
#pragma unroll
      for (int r = 0; r < 4; ++r) {
        float s = 0.f;
#pragma unroll
        for (int nf = 0; nf < 4; ++nf) s += acc[mf][nf][r] * acc[mf][nf][r];
        s += __shfl_xor(s, 1);
        s += __shfl_xor(s, 2);
        s += __shfl_xor(s, 4);
        s += __shfl_xor(s, 8);
        if (l15 == 0) {
          int row = m0 + wm * 128 + mf * 16 + lhi * 4 + r;
          if (wn == 0) {
            Q2[h * 4096 + row] = s;
          } else {
            __bf16 kh = (__bf16)s;
            __bf16 kl = (__bf16)(s - (float)kh);
            bf16x8 rw;
            rw[0] = kh; rw[1] = kl;
            rw[2] = (__bf16)1.f; rw[3] = (__bf16)1.f;
            rw[4] = (__bf16)0.f; rw[5] = (__bf16)0.f;
            rw[6] = (__bf16)0.f; rw[7] = (__bf16)0.f;
            *(bf16x8*)&K2E[((size_t)h * 4096 + row) * 8] = rw;
          }
        }
      }
  }

  bf16_t* T = &As[0][0][0];  // [64][264] = 33.8KB
  if (wn == 2) {
#pragma unroll
    for (int mf = 0; mf < 8; ++mf)
#pragma unroll
      for (int nf = 0; nf < 4; ++nf)
#pragma unroll
        for (int r = 0; r < 4; ++r) {
          int row = wm * 128 + mf * 16 + lhi * 4 + r;
          int e = nf * 16 + l15;
          int prow = (row & ~15) | ((row & 3) | ((row & 4) << 1) | ((row & 8) >> 1));
          T[e * 264 + prow] = (bf16_t)acc[mf][nf][r];
        }
  }
  __syncthreads();
  {
    int e = tid >> 3, c0 = (tid & 7) * 32;
    bf16_t* dst = VtG + (size_t)(h * 64 + e) * 4096 + m0 + c0;
#pragma unroll
    for (int j = 0; j < 4; ++j)
      *(bf16x8*)&dst[j * 8] = *(bf16x8*)&T[e * 264 + c0 + j * 8];
  }
}

// ------------------------------------------------------------------- gemm2
template <int OUTF32>
__global__ __launch_bounds__(256, 2) void gemm_kernel(
    const bf16_t* __restrict__ A, const bf16_t* __restrict__ Bt,
    const float* __restrict__ bias, void* __restrict__ Cout,
    int M, int N, int K) {
  __shared__ bf16_t As[2][128 * 64];
  __shared__ bf16_t Bs[2][128 * 64];
  int tid = threadIdx.x, lane = tid & 63, wv = tid >> 6;
  int l15 = lane & 15, lhi = lane >> 4;
  int NT = N >> 7;
  int nwg = gridDim.x;
  int qq = nwg >> 3;
  int swz = (blockIdx.x & 7) * qq + (blockIdx.x >> 3);
  int tm = swz / NT, tn = swz % NT;
  int m0 = tm << 7, n0 = tn << 7;
  int wm = (wv >> 1) << 6, wn = (wv & 1) << 6;
  int KT = K >> 6;

  auto stage = [&](int buf, int kt) {
    int k0 = kt << 6;
#pragma unroll
    for (int s = 0; s < 4; ++s) {
      int t = s * 256 + tid;
      int row = t >> 3, u = t & 7;
      int cc = (u ^ (row & 7)) << 3;
      GLDS16(A + (size_t)(m0 + row) * K + k0 + cc, &As[buf][t * 8]);
    }
#pragma unroll
    for (int s = 0; s < 4; ++s) {
      int t = s * 256 + tid;
      int row = t >> 3, u = t & 7;
      int cc = (u ^ (row & 7)) << 3;
      GLDS16(Bt + (size_t)(n0 + row) * K + k0 + cc, &Bs[buf][t * 8]);
    }
  };

  f32x4 zero = {0.f, 0.f, 0.f, 0.f};
  f32x4 acc[4][4];
#pragma unroll
  for (int ms = 0; ms < 4; ++ms)
#pragma unroll
    for (int ns = 0; ns < 4; ++ns) acc[ms][ns] = zero;

  stage(0, 0);
  __syncthreads();
  int cur = 0;
  for (int kt = 0; kt < KT; ++kt) {
    if (kt + 1 < KT) stage(cur ^ 1, kt + 1);
#pragma unroll
    for (int ks = 0; ks < 2; ++ks) {
      bf16x8 af[4], bfr[4];
#pragma unroll
      for (int ms = 0; ms < 4; ++ms) {
        int row = wm + ms * 16 + l15;
        af[ms] = *(const bf16x8*)&As[cur][row * 64 + (((ks * 4 + lhi) ^ (row & 7)) << 3)];
      }
#pragma unroll
      for (int ns = 0; ns < 4; ++ns) {
        int col = wn + ns * 16 + l15;
        bfr[ns] = *(const bf16x8*)&Bs[cur][col * 64 + (((ks * 4 + lhi) ^ (col & 7)) << 3)];
      }
#pragma unroll
      for (int ms = 0; ms < 4; ++ms)
#pragma unroll
        for (int ns = 0; ns < 4; ++ns)
          acc[ms][ns] = mfma_bf16(af[ms], bfr[ns], acc[ms][ns]);
    }
    __syncthreads();
    cur ^= 1;
  }

#pragma unroll
  for (int ns = 0; ns < 4; ++ns) {
    int col = n0 + wn + ns * 16 + l15;
    float bv = bias[col];
#pragma unroll
    for (int ms = 0; ms < 4; ++ms) {
      int rowb = m0 + wm + ms * 16 + lhi * 4;
#pragma unroll
      for (int r = 0; r < 4; ++r) {
        float v = acc[ms][ns][r] + bv;
        if (OUTF32)
          ((float*)Cout)[(size_t)(rowb + r) * N + col] = v;
        else
          ((bf16_t*)Cout)[(size_t)(rowb + r) * N + col] = (bf16_t)v;
      }
    }
  }
}

// ------------------------------------------------------- fused Shepard attention
// (R12 form — best measured: 57.2us over 4 independent runs.) 64-s tiles,
// launch_bounds(512,4), 8 waves (4 qw x 2 sw), double-buffered K/V/K2E,
// issue-early prefetch, one barrier per tile; d2 seed via seed-MFMA;
// denominator via VALU+shfl. Refuted alternatives: counted-vmcnt 4-ring
// (R16, +1.2us), 2-tile ILP unroll (R18, +25us: L2 locality destroyed).
__global__ __launch_bounds__(512, 4) void attn_kernel(
    const bf16_t* __restrict__ P, const bf16_t* __restrict__ VtG,
    const float* __restrict__ Q2, const bf16_t* __restrict__ K2E,
    bf16_t* __restrict__ H) {
  __shared__ union Smem {
    struct {
      bf16_t Ks[2][64 * 64];   // 16KB
      bf16_t Vts[2][64 * 64];  // 16KB
      bf16_t K2e[2][64 * 8];   // 2KB
    } l;
    float Comb[4][64][33];     // 33.8KB
  } sm;
  __shared__ float invLds[4][32];

  int tid = threadIdx.x, lane = tid & 63, wv = tid >> 6;
  int l31 = lane & 31, hi = lane >> 5, hi4 = hi * 4;
  int qw = wv & 3, sw = wv >> 2;
  int sOff = sw * 32;
  int swz = (blockIdx.x & 7) * 64 + (blockIdx.x >> 3);  // 512 blocks
  int hb = swz >> 4, qt = swz & 15;
  int h = hb >> 1, b = hb & 1;
  int rowbase = b * 2048;
  const bf16_t* Pq = P + (size_t)rowbase * 4096 + h * 256;
  const bf16_t* Pk = Pq + 64;
  const bf16_t* Pg = Pq + 192;
  const bf16_t* Vg = VtG + (size_t)h * 64 * 4096 + rowbase;
  const float* Q2g = Q2 + h * 4096 + rowbase;
  const bf16_t* K2Eg = K2E + ((size_t)h * 4096 + rowbase) * 8;
  int q0 = qt * 128 + qw * 32;

  auto stageKV = [&](int buf, int s0) {
    {
      int row = tid >> 3, u = tid & 7;
      int cc = (u ^ (row & 7)) << 3;
      GLDS16(Pk + (size_t)(s0 + row) * 4096 + cc, &sm.l.Ks[buf][tid * 8]);
    }
    {
      int row = tid >> 3, u = tid & 7;
      int cc = (u ^ (row & 7)) << 3;
      GLDS16(Vg + (size_t)row * 4096 + s0 + cc, &sm.l.Vts[buf][tid * 8]);
    }
    if (tid < 64)
      GLDS16(K2Eg + (size_t)(s0 + tid) * 8, &sm.l.K2e[buf][tid * 8]);
  };

  bf16x8 qm[4];
#pragma unroll
  for (int db = 0; db < 4; ++db) {
    bf16x8 q = *(const bf16x8*)(Pq + (size_t)(q0 + l31) * 4096 + db * 16 + hi * 8);
    u32x4 u = *(u32x4*)&q;
    u = (u ^ 0x80008000u) + 0x00800080u;
    qm[db] = *(bf16x8*)&u;
  }
  float q2s = Q2g[q0 + l31];
  __bf16 q2h = (__bf16)q2s;
  __bf16 q2l = (__bf16)(q2s - (float)q2h);
  bf16x8 qmE;
  qmE[0] = hi ? (__bf16)0.f : (__bf16)1.f;
  qmE[1] = qmE[0];
  qmE[2] = hi ? (__bf16)0.f : q2h;
  qmE[3] = hi ? (__bf16)0.f : q2l;
  qmE[4] = (__bf16)0.f; qmE[5] = (__bf16)0.f;
  qmE[6] = (__bf16)0.f; qmE[7] = (__bf16)0.f;

  f32x16 zero16;
#pragma unroll
  for (int r = 0; r < 16; ++r) zero16[r] = 0.f;

  f32x16 nacc0 = zero16, nacc1 = zero16;
  float dacc0 = 0.f, dacc1 = 0.f;

  stageKV(0, 0);
  __syncthreads();

  for (int st = 0; st < 32; ++st) {
    int cur = st & 1;
    int s0 = st * 64;
    if (st + 1 < 32) stageKV(cur ^ 1, s0 + 64);

    const bf16_t* KsC = sm.l.Ks[cur];
    const bf16_t* VtC = sm.l.Vts[cur];
    const bf16_t* K2eC = sm.l.K2e[cur];
    {
      int srow = sOff + l31;
      bf16x8 ke = *(const bf16x8*)&K2eC[srow * 8];
      u32x4 keu = *(u32x4*)&ke;
      u32x4 kz;
      kz[0] = hi ? 0u : keu[0];
      kz[1] = hi ? 0u : keu[1];
      kz[2] = 0u; kz[3] = 0u;
      bf16x8 kfE = *(bf16x8*)&kz;
      f32x16 D = mfma32(kfE, qmE, zero16);
#pragma unroll
      for (int db = 0; db < 4; ++db) {
        bf16x8 kf = *(const bf16x8*)&KsC[srow * 64 + (((db * 2 + hi) ^ (srow & 7)) << 3)];
        D = mfma32(kf, qm[db], D);
      }
      float p[16];
#pragma unroll
      for (int r = 0; r < 16; ++r) {
        float w = __builtin_amdgcn_rcpf(fmaxf(D[r], 1e-12f));
        if (r & 1) dacc1 += w; else dacc0 += w;
        p[r] = w;
      }
      u32x4 w0v = {cvtpk_bf16(p[0], p[1]), cvtpk_bf16(p[2], p[3]),
                   cvtpk_bf16(p[4], p[5]), cvtpk_bf16(p[6], p[7])};
      u32x4 w1v = {cvtpk_bf16(p[8], p[9]), cvtpk_bf16(p[10], p[11]),
                   cvtpk_bf16(p[12], p[13]), cvtpk_bf16(p[14], p[15])};
      bf16x8 pa0 = *(bf16x8*)&w0v;
      bf16x8 pa1 = *(bf16x8*)&w1v;
      int e = l31;
      int ciB = sw * 4;
      bf16x8 vb00 = *(const bf16x8*)&VtC[e * 64 + (((ciB + 0 + hi) ^ (e & 7)) << 3)];
      bf16x8 vb01 = *(const bf16x8*)&VtC[(e + 32) * 64 + (((ciB + 0 + hi) ^ ((e + 32) & 7)) << 3)];
      bf16x8 vb10 = *(const bf16x8*)&VtC[e * 64 + (((ciB + 2 + hi) ^ (e & 7)) << 3)];
      bf16x8 vb11 = *(const bf16x8*)&VtC[(e + 32) * 64 + (((ciB + 2 + hi) ^ ((e + 32) & 7)) << 3)];
      nacc0 = mfma32(pa0, vb00, nacc0);
      nacc1 = mfma32(pa0, vb01, nacc1);
      nacc0 = mfma32(pa1, vb10, nacc0);
      nacc1 = mfma32(pa1, vb11, nacc1);
    }
    __syncthreads();
  }

  if (sw == 1) {
#pragma unroll
    for (int r = 0; r < 16; ++r) {
      sm.Comb[qw][lane][r] = nacc0[r];
      sm.Comb[qw][lane][16 + r] = nacc1[r];
    }
    sm.Comb[qw][lane][32] = dacc0 + dacc1;
  }
  __syncthreads();
  if (sw == 0) {
    float dacc = dacc0 + dacc1 + sm.Comb[qw][lane][32];
#pragma unroll
    for (int r = 0; r < 16; ++r) {
      nacc0[r] += sm.Comb[qw][lane][r];
      nacc1[r] += sm.Comb[qw][lane][16 + r];
    }
    dacc += __shfl_xor(dacc, 32);
    float inv = __builtin_amdgcn_rcpf(ATT_EPS + dacc);
    if (lane < 32) invLds[qw][l31] = inv;
    __builtin_amdgcn_s_waitcnt(0);
#pragma unroll
    for (int r = 0; r < 16; ++r) {
      int q = (r & 3) + 8 * (r >> 2) + hi4;
      int tq = q0 + q;
      float iv = invLds[qw][q];
      float g0 = (float)Pg[(size_t)tq * 4096 + l31];
      float g1 = (float)Pg[(size_t)tq * 4096 + 32 + l31];
      H[(size_t)(rowbase + tq) * 1024 + h * 64 + l31] = (bf16_t)(g0 * nacc0[r] * iv);
      H[(size_t)(rowbase + tq) * 1024 + h * 64 + 32 + l31] = (bf16_t)(g1 * nacc1[r] * iv);
    }
  }
}

// ------------------------------------------------------------------ launcher
extern "C" void kernel_launch(void* const* d_in, const int* in_sizes, int n_in,
                              void* d_out, int out_size, void* d_ws, size_t ws_size,
                              hipStream_t stream) {
  const float* X     = (const float*)d_in[0];
  const float* W_in  = (const float*)d_in[1];
  const float* b_in  = (const float*)d_in[2];
  const float* W_out = (const float*)d_in[3];
  const float* b_out = (const float*)d_in[4];

  char* ws = (char*)d_ws;
  bf16_t* Xb  = (bf16_t*)(ws);                        // 8 MB
  bf16_t* WbT = (bf16_t*)(ws + ((size_t)8  << 20));   // 8 MB
  bf16_t* WoT = (bf16_t*)(ws + ((size_t)16 << 20));   // 2 MB
  bf16_t* Pb  = (bf16_t*)(ws + ((size_t)18 << 20));   // 32 MB
  bf16_t* Hb  = (bf16_t*)(ws + ((size_t)50 << 20));   // 8 MB
  float*  Q2  = (float*) (ws + ((size_t)58 << 20));   // 256 KB
  // VtG/K2E live in d_out (16 MB, dead until gemm2 overwrites it)
  bf16_t* VtG = (bf16_t*)d_out;                       // 8 MB
  bf16_t* K2E = (bf16_t*)((char*)d_out + ((size_t)8 << 20));  // 1 MB

  prep_kernel<<<dim3(64, 36), 256, 0, stream>>>(W_in, WbT, W_out, WoT, X, Xb);
  gemm1_kernel<<<256, 512, 0, stream>>>(Xb, WbT, b_in, Pb, Q2, K2E, VtG);
  attn_kernel<<<512, 512, 0, stream>>>(Pb, VtG, Q2, K2E, Hb);
  gemm_kernel<1><<<256, 256, 0, stream>>>(Hb, WoT, b_out, d_out, 4096, 1024, 1024);
}